// Round 1
// baseline (208.552 us; speedup 1.0000x reference)
//
#include <hip/hip_runtime.h>

#define I_TOTAL 100000
#define DIM 64
#define BS 256

typedef __attribute__((ext_vector_type(8))) short bf16x8;
typedef __attribute__((ext_vector_type(4))) float f32x4;

// Packed fp32->bf16 (RNE). No builtin on gfx950 (learn_hip m240) -> inline asm.
__device__ inline unsigned pk_bf16(float lo, float hi) {
    unsigned r;
    asm("v_cvt_pk_bf16_f32 %0, %1, %2" : "=v"(r) : "v"(lo), "v"(hi));
    return r;
}

__device__ inline bf16x8 pack8(float4 a, float4 b) {
    union { unsigned u[4]; bf16x8 v; } r;
    r.u[0] = pk_bf16(a.x, a.y);
    r.u[1] = pk_bf16(a.z, a.w);
    r.u[2] = pk_bf16(b.x, b.y);
    r.u[3] = pk_bf16(b.z, b.w);
    return r.v;
}

// Fully fused: A-prep (u*W*log2e -> bf16) in-register, fp32 items converted
// inline (8 cvt_pk/tile), bias folded into MFMA C-operand, softmax+transpose
// +store as before. 1D grid of 1664 blocks (96 idle); blk%8 keyed to i-range
// so each XCD re-reads the same 3.2 MB fp32 item slice from its L2.
// Block: 16 b x 1024 i. Wave: 16 b x 256 i (16 tiles), 5 classes.
__global__ __launch_bounds__(256) void gemm_softmax_fused(
    const int* __restrict__ bu, const float* __restrict__ ut,
    const float* __restrict__ it, const float* __restrict__ cw,
    const float* __restrict__ clsb, const float* __restrict__ vals,
    float* __restrict__ out)
{
    // per-wave private transpose buffer: 4 waves * 1056 dw = 16896 B.
    // slot(dw) = wave*1056 + quad*264 + rr*64 + ti*16 + col   (264 = 8-dw skew
    // per quad -> all LDS ops <=2-way bank aliased = free)
    __shared__ float ldsb[4224];

    const int blk = blockIdx.x;
    const int r8 = blk & 7;
    const int qq = blk >> 3;
    const int g  = qq & 15;          // b-group (16 b each)
    const int a  = qq >> 4;          // 0..12
    const int y  = a * 8 + r8;       // i-range id, 0..103
    if (y >= 98) return;

    const int lane = threadIdx.x & 63;
    const int wave = threadIdx.x >> 6;
    const int col  = lane & 15;     // A m-row (b in group) / C col (i in tile)
    const int quad = lane >> 4;

    const int b_base = g * 16;
    const int i_base = y * 1024 + wave * 256;   // this wave's 16 i-tiles

    const float s = 1.4426950408889634f;        // log2(e)

    // ---- A-prep in-register (replaces prep_M + Mbf round-trip) ----
    // lane (col,quad) owns M[c*256 + b_base+col][quad*8..+8, 32+quad*8..+8]
    const float* up = ut + (size_t)bu[b_base + col] * DIM + quad * 8;
    float4 u0 = *(const float4*)(up);
    float4 u1 = *(const float4*)(up + 4);
    float4 u2 = *(const float4*)(up + 32);
    float4 u3 = *(const float4*)(up + 36);
    u0.x *= s; u0.y *= s; u0.z *= s; u0.w *= s;
    u1.x *= s; u1.y *= s; u1.z *= s; u1.w *= s;
    u2.x *= s; u2.y *= s; u2.z *= s; u2.w *= s;
    u3.x *= s; u3.y *= s; u3.z *= s; u3.w *= s;

    bf16x8 afr[5][2];
    f32x4 cin[5];                   // bias*log2e broadcast -> free add via MFMA C
    float vv[5];
#pragma unroll
    for (int c = 0; c < 5; ++c) {
        const float* wp = cw + c * DIM + quad * 8;
        float4 w0 = *(const float4*)(wp);
        float4 w1 = *(const float4*)(wp + 4);
        float4 w2 = *(const float4*)(wp + 32);
        float4 w3 = *(const float4*)(wp + 36);
        float4 m0 = make_float4(u0.x*w0.x, u0.y*w0.y, u0.z*w0.z, u0.w*w0.w);
        float4 m1 = make_float4(u1.x*w1.x, u1.y*w1.y, u1.z*w1.z, u1.w*w1.w);
        float4 m2 = make_float4(u2.x*w2.x, u2.y*w2.y, u2.z*w2.z, u2.w*w2.w);
        float4 m3 = make_float4(u3.x*w3.x, u3.y*w3.y, u3.z*w3.z, u3.w*w3.w);
        afr[c][0] = pack8(m0, m1);
        afr[c][1] = pack8(m2, m3);
        float bc = clsb[c] * s;
        cin[c] = (f32x4){bc, bc, bc, bc};
        vv[c] = vals[c];
    }

    if (y < 97) {
        // ---- fast path ----
        float* wlds = ldsb + wave * 1056 + quad * 264 + col;          // write base
        const float* rlds = ldsb + wave * 1056 + quad * 264 + 4 * col; // read base

        float* op[4];
#pragma unroll
        for (int k = 0; k < 4; ++k)
            op[k] = out + (size_t)(b_base + quad * 4 + k) * I_TOTAL + (i_base + 4 * col);

        const float* bp = it + (size_t)(i_base + col) * DIM + quad * 8;

#pragma unroll 1
        for (int t4 = 0; t4 < 4; ++t4) {
#pragma unroll
            for (int ti = 0; ti < 4; ++ti) {
                const float* p = bp + ti * 1024;
                float4 q0 = *(const float4*)(p);
                float4 q1 = *(const float4*)(p + 4);
                float4 q2 = *(const float4*)(p + 32);
                float4 q3 = *(const float4*)(p + 36);
                bf16x8 b0 = pack8(q0, q1);
                bf16x8 b1 = pack8(q2, q3);
                f32x4 acc[5];
#pragma unroll
                for (int c = 0; c < 5; ++c) {
                    acc[c] = __builtin_amdgcn_mfma_f32_16x16x32_bf16(afr[c][0], b0, cin[c], 0, 0, 0);
                    acc[c] = __builtin_amdgcn_mfma_f32_16x16x32_bf16(afr[c][1], b1, acc[c], 0, 0, 0);
                }
                // acc already holds log2e*(dot + bias): exp2 directly
#pragma unroll
                for (int rr = 0; rr < 4; ++rr) {
                    float e0 = __builtin_amdgcn_exp2f(acc[0][rr]);
                    float e1 = __builtin_amdgcn_exp2f(acc[1][rr]);
                    float e2 = __builtin_amdgcn_exp2f(acc[2][rr]);
                    float e3 = __builtin_amdgcn_exp2f(acc[3][rr]);
                    float e4 = __builtin_amdgcn_exp2f(acc[4][rr]);
                    float den = ((e0 + e1) + (e2 + e3)) + e4;
                    float num = e0 * vv[0];
                    num = fmaf(e1, vv[1], num);
                    num = fmaf(e2, vv[2], num);
                    num = fmaf(e3, vv[3], num);
                    num = fmaf(e4, vv[4], num);
                    wlds[rr * 64 + ti * 16] = num * __builtin_amdgcn_rcpf(den);
                }
            }
            // transpose read-back: round k = b-row within quad; 1-KB wave stores
#pragma unroll
            for (int k = 0; k < 4; ++k) {
                f32x4 o4 = *(const f32x4*)(rlds + k * 64);
                *(f32x4*)op[k] = o4;
                op[k] += 64;
            }
            bp += 4 * 1024;
        }
    } else {
        // ---- tail path (y == 97): clamp loads, guard stores ----
#pragma unroll 1
        for (int t = 0; t < 16; ++t) {
            int i  = i_base + t * 16 + col;
            int ic = i < I_TOTAL ? i : I_TOTAL - 1;
            const float* p2 = it + (size_t)ic * DIM + quad * 8;
            float4 q0 = *(const float4*)(p2);
            float4 q1 = *(const float4*)(p2 + 4);
            float4 q2 = *(const float4*)(p2 + 32);
            float4 q3 = *(const float4*)(p2 + 36);
            bf16x8 b0 = pack8(q0, q1);
            bf16x8 b1 = pack8(q2, q3);
            f32x4 acc[5];
#pragma unroll
            for (int c = 0; c < 5; ++c) {
                acc[c] = __builtin_amdgcn_mfma_f32_16x16x32_bf16(afr[c][0], b0, cin[c], 0, 0, 0);
                acc[c] = __builtin_amdgcn_mfma_f32_16x16x32_bf16(afr[c][1], b1, acc[c], 0, 0, 0);
            }
            if (i < I_TOTAL) {
#pragma unroll
                for (int rr = 0; rr < 4; ++rr) {
                    float e0 = __builtin_amdgcn_exp2f(acc[0][rr]);
                    float e1 = __builtin_amdgcn_exp2f(acc[1][rr]);
                    float e2 = __builtin_amdgcn_exp2f(acc[2][rr]);
                    float e3 = __builtin_amdgcn_exp2f(acc[3][rr]);
                    float e4 = __builtin_amdgcn_exp2f(acc[4][rr]);
                    float den = ((e0 + e1) + (e2 + e3)) + e4;
                    float num = e0 * vv[0];
                    num = fmaf(e1, vv[1], num);
                    num = fmaf(e2, vv[2], num);
                    num = fmaf(e3, vv[3], num);
                    num = fmaf(e4, vv[4], num);
                    out[(size_t)(b_base + quad * 4 + rr) * I_TOTAL + i] =
                        num * __builtin_amdgcn_rcpf(den);
                }
            }
        }
    }
}

extern "C" void kernel_launch(void* const* d_in, const int* in_sizes, int n_in,
                              void* d_out, int out_size, void* d_ws, size_t ws_size,
                              hipStream_t stream) {
    const int*   bu   = (const int*)d_in[0];
    const float* ut   = (const float*)d_in[1];
    const float* it   = (const float*)d_in[2];
    const float* cw   = (const float*)d_in[3];
    const float* cb   = (const float*)d_in[4];
    const float* vals = (const float*)d_in[5];
    float* out = (float*)d_out;
    (void)d_ws; (void)ws_size; (void)in_sizes; (void)n_in; (void)out_size;

    // Single fused dispatch: no workspace, no inter-kernel dependencies.
    gemm_softmax_fused<<<1664, 256, 0, stream>>>(bu, ut, it, cw, cb, vals, out);
}

// Round 2
// 176.915 us; speedup vs baseline: 1.1788x; 1.1788x over previous
//
#include <hip/hip_runtime.h>

#define I_TOTAL 100000
#define DIM 64
#define BS 256

typedef __attribute__((ext_vector_type(8))) short bf16x8;
typedef __attribute__((ext_vector_type(4))) float f32x4;

__device__ inline unsigned short f2bf(float x) {
    union { float f; unsigned u; } v; v.f = x;
    return (unsigned short)((v.u + 0x8000u) >> 16);   // round-half-up to bf16
}

// Packed fp32->bf16 (RNE). No builtin on gfx950 -> inline asm.
__device__ inline unsigned pk_bf16(float lo, float hi) {
    unsigned r;
    asm("v_cvt_pk_bf16_f32 %0, %1, %2" : "=v"(r) : "v"(lo), "v"(hi));
    return r;
}

__device__ inline bf16x8 pack8(float4 a, float4 b) {
    union { unsigned u[4]; bf16x8 v; } r;
    r.u[0] = pk_bf16(a.x, a.y);
    r.u[1] = pk_bf16(a.z, a.w);
    r.u[2] = pk_bf16(b.x, b.y);
    r.u[3] = pk_bf16(b.z, b.w);
    return r.v;
}

// Convert item table fp32 -> bf16 once (BW-bound, ~6.5 us).
__global__ __launch_bounds__(256) void conv_items(
    const float* __restrict__ item, unsigned short* __restrict__ itbf)
{
    long t = (long)blockIdx.x * 256 + threadIdx.x;   // 0..799999
    const float4* p = (const float4*)(item + t * 8);
    float4 a = p[0], b = p[1];
    ushort4 r0, r1;
    r0.x = f2bf(a.x); r0.y = f2bf(a.y); r0.z = f2bf(a.z); r0.w = f2bf(a.w);
    r1.x = f2bf(b.x); r1.y = f2bf(b.y); r1.z = f2bf(b.z); r1.w = f2bf(b.w);
    ushort4* q = (ushort4*)(itbf + t * 8);
    q[0] = r0; q[1] = r1;
}

// Main kernel: bf16 item loads (R0's fast path) + in-register A-prep and
// bias-in-MFMA-C (R1's verified wins) + explicit 1-tile-ahead B prefetch.
// 1D grid of 1664 blocks (96 idle); blk%8 keyed to i-range so each XCD
// re-reads the same bf16 item slice from its L2 (FETCH ~8 MB).
// Block: 16 b x 1024 i. Wave: 16 b x 256 i (16 tiles), 5 classes.
__global__ __launch_bounds__(256) void gemm_softmax(
    const unsigned short* __restrict__ itbf,
    const int* __restrict__ bu, const float* __restrict__ ut,
    const float* __restrict__ cw, const float* __restrict__ clsb,
    const float* __restrict__ vals, float* __restrict__ out)
{
    // per-wave private transpose buffer: 4 waves * 1056 dw = 16896 B.
    // slot(dw) = wave*1056 + quad*264 + rr*64 + ti*16 + col   (264 = 8-dw skew
    // per quad -> all LDS ops <=2-way bank aliased = free)
    __shared__ float ldsb[4224];

    const int blk = blockIdx.x;
    const int r8 = blk & 7;
    const int qq = blk >> 3;
    const int g  = qq & 15;          // b-group (16 b each)
    const int a  = qq >> 4;          // 0..12
    const int y  = a * 8 + r8;       // i-range id, 0..103
    if (y >= 98) return;

    const int lane = threadIdx.x & 63;
    const int wave = threadIdx.x >> 6;
    const int col  = lane & 15;     // A m-row (b in group) / C col (i in tile)
    const int quad = lane >> 4;

    const int b_base = g * 16;
    const int i_base = y * 1024 + wave * 256;   // this wave's 16 i-tiles

    const float s = 1.4426950408889634f;        // log2(e)

    // ---- A-prep in-register (replaces prep_M + Mbf round-trip) ----
    // lane (col,quad) owns M[c][b_base+col][quad*8..+8, 32+quad*8..+8],
    // M = u * W * log2e in bf16.
    const float* up = ut + (size_t)bu[b_base + col] * DIM + quad * 8;
    float4 u0 = *(const float4*)(up);
    float4 u1 = *(const float4*)(up + 4);
    float4 u2 = *(const float4*)(up + 32);
    float4 u3 = *(const float4*)(up + 36);
    u0.x *= s; u0.y *= s; u0.z *= s; u0.w *= s;
    u1.x *= s; u1.y *= s; u1.z *= s; u1.w *= s;
    u2.x *= s; u2.y *= s; u2.z *= s; u2.w *= s;
    u3.x *= s; u3.y *= s; u3.z *= s; u3.w *= s;

    bf16x8 afr[5][2];
    f32x4 cin[5];                   // bias*log2e broadcast -> free add via MFMA C
    float vv[5];
#pragma unroll
    for (int c = 0; c < 5; ++c) {
        const float* wp = cw + c * DIM + quad * 8;
        float4 w0 = *(const float4*)(wp);
        float4 w1 = *(const float4*)(wp + 4);
        float4 w2 = *(const float4*)(wp + 32);
        float4 w3 = *(const float4*)(wp + 36);
        float4 m0 = make_float4(u0.x*w0.x, u0.y*w0.y, u0.z*w0.z, u0.w*w0.w);
        float4 m1 = make_float4(u1.x*w1.x, u1.y*w1.y, u1.z*w1.z, u1.w*w1.w);
        float4 m2 = make_float4(u2.x*w2.x, u2.y*w2.y, u2.z*w2.z, u2.w*w2.w);
        float4 m3 = make_float4(u3.x*w3.x, u3.y*w3.y, u3.z*w3.z, u3.w*w3.w);
        afr[c][0] = pack8(m0, m1);
        afr[c][1] = pack8(m2, m3);
        float bc = clsb[c] * s;
        cin[c] = (f32x4){bc, bc, bc, bc};
        vv[c] = vals[c];
    }

    if (y < 97) {
        // ---- fast path ----
        float* wlds = ldsb + wave * 1056 + quad * 264 + col;           // write base
        const float* rlds = ldsb + wave * 1056 + quad * 264 + 4 * col; // read base

        float* op[4];
#pragma unroll
        for (int k = 0; k < 4; ++k)
            op[k] = out + (size_t)(b_base + quad * 4 + k) * I_TOTAL + (i_base + 4 * col);

        const unsigned short* bp = itbf + (size_t)(i_base + col) * DIM + quad * 8;

        // Prefetch tile 0. Prefetching tile t+1 is always in-bounds for the
        // fast path: max row touched = i_base+col+256 <= 99583 < 100000.
        bf16x8 nb0 = *(const bf16x8*)(bp);
        bf16x8 nb1 = *(const bf16x8*)(bp + 32);

#pragma unroll 1
        for (int t4 = 0; t4 < 4; ++t4) {
#pragma unroll
            for (int ti = 0; ti < 4; ++ti) {
                bf16x8 b0 = nb0, b1 = nb1;
                const unsigned short* np = bp + (t4 * 4 + ti + 1) * 1024;
                nb0 = *(const bf16x8*)(np);
                nb1 = *(const bf16x8*)(np + 32);
                f32x4 acc[5];
#pragma unroll
                for (int c = 0; c < 5; ++c) {
                    acc[c] = __builtin_amdgcn_mfma_f32_16x16x32_bf16(afr[c][0], b0, cin[c], 0, 0, 0);
                    acc[c] = __builtin_amdgcn_mfma_f32_16x16x32_bf16(afr[c][1], b1, acc[c], 0, 0, 0);
                }
                // acc already holds log2e*(dot + bias): exp2 directly
#pragma unroll
                for (int rr = 0; rr < 4; ++rr) {
                    float e0 = __builtin_amdgcn_exp2f(acc[0][rr]);
                    float e1 = __builtin_amdgcn_exp2f(acc[1][rr]);
                    float e2 = __builtin_amdgcn_exp2f(acc[2][rr]);
                    float e3 = __builtin_amdgcn_exp2f(acc[3][rr]);
                    float e4 = __builtin_amdgcn_exp2f(acc[4][rr]);
                    float den = ((e0 + e1) + (e2 + e3)) + e4;
                    float num = e0 * vv[0];
                    num = fmaf(e1, vv[1], num);
                    num = fmaf(e2, vv[2], num);
                    num = fmaf(e3, vv[3], num);
                    num = fmaf(e4, vv[4], num);
                    wlds[rr * 64 + ti * 16] = num * __builtin_amdgcn_rcpf(den);
                }
            }
            // transpose read-back: round k = b-row within quad; 1-KB wave stores
#pragma unroll
            for (int k = 0; k < 4; ++k) {
                f32x4 o4 = *(const f32x4*)(rlds + k * 64);
                *(f32x4*)op[k] = o4;
                op[k] += 64;
            }
        }
    } else {
        // ---- tail path (y == 97): clamp loads, guard stores ----
#pragma unroll 1
        for (int t = 0; t < 16; ++t) {
            int i  = i_base + t * 16 + col;
            int ic = i < I_TOTAL ? i : I_TOTAL - 1;
            const unsigned short* p2 = itbf + (size_t)ic * DIM + quad * 8;
            bf16x8 b0 = *(const bf16x8*)p2;
            bf16x8 b1 = *(const bf16x8*)(p2 + 32);
            f32x4 acc[5];
#pragma unroll
            for (int c = 0; c < 5; ++c) {
                acc[c] = __builtin_amdgcn_mfma_f32_16x16x32_bf16(afr[c][0], b0, cin[c], 0, 0, 0);
                acc[c] = __builtin_amdgcn_mfma_f32_16x16x32_bf16(afr[c][1], b1, acc[c], 0, 0, 0);
            }
            if (i < I_TOTAL) {
#pragma unroll
                for (int rr = 0; rr < 4; ++rr) {
                    float e0 = __builtin_amdgcn_exp2f(acc[0][rr]);
                    float e1 = __builtin_amdgcn_exp2f(acc[1][rr]);
                    float e2 = __builtin_amdgcn_exp2f(acc[2][rr]);
                    float e3 = __builtin_amdgcn_exp2f(acc[3][rr]);
                    float e4 = __builtin_amdgcn_exp2f(acc[4][rr]);
                    float den = ((e0 + e1) + (e2 + e3)) + e4;
                    float num = e0 * vv[0];
                    num = fmaf(e1, vv[1], num);
                    num = fmaf(e2, vv[2], num);
                    num = fmaf(e3, vv[3], num);
                    num = fmaf(e4, vv[4], num);
                    out[(size_t)(b_base + quad * 4 + rr) * I_TOTAL + i] =
                        num * __builtin_amdgcn_rcpf(den);
                }
            }
        }
    }
}

// Fallback (no workspace): R1's fused fp32-load kernel (passed, 94.9 us).
__global__ __launch_bounds__(256) void gemm_softmax_fb(
    const int* __restrict__ bu, const float* __restrict__ ut,
    const float* __restrict__ it, const float* __restrict__ cw,
    const float* __restrict__ clsb, const float* __restrict__ vals,
    float* __restrict__ out)
{
    __shared__ float ldsb[4224];

    const int blk = blockIdx.x;
    const int r8 = blk & 7;
    const int qq = blk >> 3;
    const int g  = qq & 15;
    const int a  = qq >> 4;
    const int y  = a * 8 + r8;
    if (y >= 98) return;

    const int lane = threadIdx.x & 63;
    const int wave = threadIdx.x >> 6;
    const int col  = lane & 15;
    const int quad = lane >> 4;

    const int b_base = g * 16;
    const int i_base = y * 1024 + wave * 256;

    const float s = 1.4426950408889634f;

    const float* up = ut + (size_t)bu[b_base + col] * DIM + quad * 8;
    float4 u0 = *(const float4*)(up);
    float4 u1 = *(const float4*)(up + 4);
    float4 u2 = *(const float4*)(up + 32);
    float4 u3 = *(const float4*)(up + 36);
    u0.x *= s; u0.y *= s; u0.z *= s; u0.w *= s;
    u1.x *= s; u1.y *= s; u1.z *= s; u1.w *= s;
    u2.x *= s; u2.y *= s; u2.z *= s; u2.w *= s;
    u3.x *= s; u3.y *= s; u3.z *= s; u3.w *= s;

    bf16x8 afr[5][2];
    f32x4 cin[5];
    float vv[5];
#pragma unroll
    for (int c = 0; c < 5; ++c) {
        const float* wp = cw + c * DIM + quad * 8;
        float4 w0 = *(const float4*)(wp);
        float4 w1 = *(const float4*)(wp + 4);
        float4 w2 = *(const float4*)(wp + 32);
        float4 w3 = *(const float4*)(wp + 36);
        float4 m0 = make_float4(u0.x*w0.x, u0.y*w0.y, u0.z*w0.z, u0.w*w0.w);
        float4 m1 = make_float4(u1.x*w1.x, u1.y*w1.y, u1.z*w1.z, u1.w*w1.w);
        float4 m2 = make_float4(u2.x*w2.x, u2.y*w2.y, u2.z*w2.z, u2.w*w2.w);
        float4 m3 = make_float4(u3.x*w3.x, u3.y*w3.y, u3.z*w3.z, u3.w*w3.w);
        afr[c][0] = pack8(m0, m1);
        afr[c][1] = pack8(m2, m3);
        float bc = clsb[c] * s;
        cin[c] = (f32x4){bc, bc, bc, bc};
        vv[c] = vals[c];
    }

    if (y < 97) {
        float* wlds = ldsb + wave * 1056 + quad * 264 + col;
        const float* rlds = ldsb + wave * 1056 + quad * 264 + 4 * col;

        float* op[4];
#pragma unroll
        for (int k = 0; k < 4; ++k)
            op[k] = out + (size_t)(b_base + quad * 4 + k) * I_TOTAL + (i_base + 4 * col);

        const float* bp = it + (size_t)(i_base + col) * DIM + quad * 8;

#pragma unroll 1
        for (int t4 = 0; t4 < 4; ++t4) {
#pragma unroll
            for (int ti = 0; ti < 4; ++ti) {
                const float* p = bp + ti * 1024;
                float4 q0 = *(const float4*)(p);
                float4 q1 = *(const float4*)(p + 4);
                float4 q2 = *(const float4*)(p + 32);
                float4 q3 = *(const float4*)(p + 36);
                bf16x8 b0 = pack8(q0, q1);
                bf16x8 b1 = pack8(q2, q3);
                f32x4 acc[5];
#pragma unroll
                for (int c = 0; c < 5; ++c) {
                    acc[c] = __builtin_amdgcn_mfma_f32_16x16x32_bf16(afr[c][0], b0, cin[c], 0, 0, 0);
                    acc[c] = __builtin_amdgcn_mfma_f32_16x16x32_bf16(afr[c][1], b1, acc[c], 0, 0, 0);
                }
#pragma unroll
                for (int rr = 0; rr < 4; ++rr) {
                    float e0 = __builtin_amdgcn_exp2f(acc[0][rr]);
                    float e1 = __builtin_amdgcn_exp2f(acc[1][rr]);
                    float e2 = __builtin_amdgcn_exp2f(acc[2][rr]);
                    float e3 = __builtin_amdgcn_exp2f(acc[3][rr]);
                    float e4 = __builtin_amdgcn_exp2f(acc[4][rr]);
                    float den = ((e0 + e1) + (e2 + e3)) + e4;
                    float num = e0 * vv[0];
                    num = fmaf(e1, vv[1], num);
                    num = fmaf(e2, vv[2], num);
                    num = fmaf(e3, vv[3], num);
                    num = fmaf(e4, vv[4], num);
                    wlds[rr * 64 + ti * 16] = num * __builtin_amdgcn_rcpf(den);
                }
            }
#pragma unroll
            for (int k = 0; k < 4; ++k) {
                f32x4 o4 = *(const f32x4*)(rlds + k * 64);
                *(f32x4*)op[k] = o4;
                op[k] += 64;
            }
            bp += 4 * 1024;
        }
    } else {
#pragma unroll 1
        for (int t = 0; t < 16; ++t) {
            int i  = i_base + t * 16 + col;
            int ic = i < I_TOTAL ? i : I_TOTAL - 1;
            const float* p2 = it + (size_t)ic * DIM + quad * 8;
            float4 q0 = *(const float4*)(p2);
            float4 q1 = *(const float4*)(p2 + 4);
            float4 q2 = *(const float4*)(p2 + 32);
            float4 q3 = *(const float4*)(p2 + 36);
            bf16x8 b0 = pack8(q0, q1);
            bf16x8 b1 = pack8(q2, q3);
            f32x4 acc[5];
#pragma unroll
            for (int c = 0; c < 5; ++c) {
                acc[c] = __builtin_amdgcn_mfma_f32_16x16x32_bf16(afr[c][0], b0, cin[c], 0, 0, 0);
                acc[c] = __builtin_amdgcn_mfma_f32_16x16x32_bf16(afr[c][1], b1, acc[c], 0, 0, 0);
            }
            if (i < I_TOTAL) {
#pragma unroll
                for (int rr = 0; rr < 4; ++rr) {
                    float e0 = __builtin_amdgcn_exp2f(acc[0][rr]);
                    float e1 = __builtin_amdgcn_exp2f(acc[1][rr]);
                    float e2 = __builtin_amdgcn_exp2f(acc[2][rr]);
                    float e3 = __builtin_amdgcn_exp2f(acc[3][rr]);
                    float e4 = __builtin_amdgcn_exp2f(acc[4][rr]);
                    float den = ((e0 + e1) + (e2 + e3)) + e4;
                    float num = e0 * vv[0];
                    num = fmaf(e1, vv[1], num);
                    num = fmaf(e2, vv[2], num);
                    num = fmaf(e3, vv[3], num);
                    num = fmaf(e4, vv[4], num);
                    out[(size_t)(b_base + quad * 4 + rr) * I_TOTAL + i] =
                        num * __builtin_amdgcn_rcpf(den);
                }
            }
        }
    }
}

extern "C" void kernel_launch(void* const* d_in, const int* in_sizes, int n_in,
                              void* d_out, int out_size, void* d_ws, size_t ws_size,
                              hipStream_t stream) {
    const int*   bu   = (const int*)d_in[0];
    const float* ut   = (const float*)d_in[1];
    const float* it   = (const float*)d_in[2];
    const float* cw   = (const float*)d_in[3];
    const float* cb   = (const float*)d_in[4];
    const float* vals = (const float*)d_in[5];
    float* out = (float*)d_out;
    unsigned short* itbf = (unsigned short*)d_ws;    // 12.8 MB

    const size_t needed = (size_t)I_TOTAL * DIM * 2;

    if (ws_size >= needed) {
        conv_items<<<3125, 256, 0, stream>>>(it, itbf);
        gemm_softmax<<<1664, 256, 0, stream>>>(itbf, bu, ut, cw, cb, vals, out);
    } else {
        gemm_softmax_fb<<<1664, 256, 0, stream>>>(bu, ut, it, cw, cb, vals, out);
    }
}